// Round 10
// baseline (618.951 us; speedup 1.0000x reference)
//
#include <hip/hip_runtime.h>
#include <hip/hip_bf16.h>

// Problem: B=2, Ccat=128, OUT=64, H=W=256, f32 in/out storage, bf16-grade 2% tol.
// Pipeline:
//   prep: weights -> [tap][oc][ic] bf16; zero stats
//   xpose: x2 NCHW -> xcat NHWC lower 64ch
//   upmfma: convT2x2 (MFMA, 4 parity GEMMs) -> xcat upper 64ch + planar XPU
//   offconv (MFMA, row-streamed LDS dbuf, 4 blocks/CU): 128->256 -> off NCHW
//   gather: bilinear deform (planar sources) -> xd NHWC bf16
//   conv1 (MFMA, 1024-block grid) + bias -> c1o NHWC; stats; bnrelu -> h1 NHWC
//   conv2 (MFMA, 1024-block grid) + bias -> c2o NHWC; stats; bnrelu+xpose -> d_out
// g_ws: xcat 0..32Mi | off 32..96Mi | xd 96..128Mi | c1o 128..144Mi | h1 144..160Mi
//       c2o 160..176Mi | Wo/W1/W2 176Mi..176Mi+811008 | XPU 177..193Mi

typedef short short8 __attribute__((ext_vector_type(8)));
typedef short short4v __attribute__((ext_vector_type(4)));
typedef float f32x4 __attribute__((ext_vector_type(4)));

__device__ unsigned char g_ws[193u << 20] __attribute__((aligned(256)));
__device__ float g_st[256];

#define OFF_XCAT 0u
#define OFF_OFF  (32u << 20)
#define OFF_XD   (96u << 20)
#define OFF_C1O  (128u << 20)
#define OFF_H1   (144u << 20)
#define OFF_C2O  (160u << 20)
#define OFF_WO   (176u << 20)
#define OFF_W1   ((176u << 20) + 589824u)
#define OFF_W2   ((176u << 20) + 737280u)
#define OFF_XPU  (177u << 20)

__device__ __forceinline__ float b2f(__hip_bfloat16 v) { return __bfloat162float(v); }
__device__ __forceinline__ short f2b(float v) {
  __hip_bfloat16 h = __float2bfloat16(v); short s; __builtin_memcpy(&s, &h, 2); return s;
}
__device__ __forceinline__ float s2f(short s) {
  __hip_bfloat16 h; __builtin_memcpy(&h, &s, 2); return __bfloat162float(h);
}

// ---------- prep: weight transforms (OIHW f32 -> [tap][oc][ic] bf16) + zero stats ----------
__global__ __launch_bounds__(256)
void k_prep(const float* __restrict__ offw, const float* __restrict__ c1w,
            const float* __restrict__ c2w) {
  const int fid = blockIdx.x * 256 + threadIdx.x;
  if (blockIdx.x == 0) g_st[threadIdx.x] = 0.f;
  __hip_bfloat16* Wo = (__hip_bfloat16*)(g_ws + OFF_WO);
  __hip_bfloat16* W1 = (__hip_bfloat16*)(g_ws + OFF_W1);
  __hip_bfloat16* W2 = (__hip_bfloat16*)(g_ws + OFF_W2);
  if (fid < 294912) {            // Wo: (tap*256+oc)*128+ic
    int ic = fid & 127, rest = fid >> 7, oc = rest & 255, tap = rest >> 8;
    Wo[fid] = __float2bfloat16(offw[(oc * 128 + ic) * 9 + tap]);
  } else if (fid < 368640) {     // W1: (tap*64+oc)*128+ic
    int l = fid - 294912;
    int ic = l & 127, rest = l >> 7, oc = rest & 63, tap = rest >> 6;
    W1[l] = __float2bfloat16(c1w[(oc * 128 + ic) * 9 + tap]);
  } else {                       // W2: (tap*64+oc)*64+ic
    int l = fid - 368640;
    int ic = l & 63, rest = l >> 6, oc = rest & 63, tap = rest >> 6;
    W2[l] = __float2bfloat16(c2w[(oc * 64 + ic) * 9 + tap]);
  }
}

// ---------- xpose: x2 NCHW f32 -> xcat NHWC bf16 lower 64 channels ----------
__global__ __launch_bounds__(256)
void k_xpose(const float* __restrict__ x2) {
  __shared__ short T[256][72];
  const int t = threadIdx.x;
  const int h = blockIdx.x & 255, b = blockIdx.x >> 8;
  const float* src = x2 + (size_t)(b * 64) * 65536 + h * 256;
  for (int rep = 0; rep < 64; ++rep) {
    int flat = rep * 256 + t, c = flat >> 8, w = flat & 255;
    T[w][c] = f2b(src[(size_t)c * 65536 + w]);
  }
  __syncthreads();
  short* xcat = (short*)(g_ws + OFF_XCAT) + ((size_t)(b * 256 + h) * 256) * 128;
  for (int rep = 0; rep < 8; ++rep) {
    int unit = rep * 256 + t;  // w*8+cg
    int w = unit >> 3, cg = unit & 7;
    *(short8*)(xcat + (size_t)w * 128 + cg * 8) = *(short8*)(&T[w][cg * 8]);
  }
}

// ---------- upmfma: convT(2x2,s2) via 4 parity GEMMs -> xcat upper + XPU planar ----------
__global__ __launch_bounds__(256)
void k_upmfma(const float* __restrict__ x1, const float* __restrict__ up_w,
              const float* __restrict__ up_b) {
  __shared__ short W4[4][64][66];   // [k*2+l][o][i]
  __shared__ short X[64][68];       // [ws][i]
  __shared__ short U[2][128][66];   // [k][wl][o]
  __shared__ float BS[64];
  const int t = threadIdx.x;
  const int half = blockIdx.x & 1, hs = (blockIdx.x >> 1) & 127, b = blockIdx.x >> 8;
  for (int rep = 0; rep < 64; ++rep) {
    int flat = rep * 256 + t;
    int i = flat >> 8, rest = flat & 255, o = rest >> 2, kl = rest & 3;
    W4[kl][o][i] = f2b(up_w[flat]);
  }
  if (t < 64) BS[t] = up_b[t];
  const float* x1b = x1 + (size_t)(b * 64) * 16384 + hs * 128 + half * 64;
  for (int rep = 0; rep < 16; ++rep) {
    int flat = rep * 256 + t;
    int i = flat >> 6, ws = flat & 63;
    X[ws][i] = f2b(x1b[(size_t)i * 16384 + ws]);
  }
  __syncthreads();
  const int wv = t >> 6, lane = t & 63, l15 = lane & 15, quad = lane >> 4;
  short8 bf[2];
#pragma unroll
  for (int ks = 0; ks < 2; ++ks)
    bf[ks] = *(const short8*)(&X[wv * 16 + l15][ks * 32 + quad * 8]);
#pragma unroll
  for (int combo = 0; combo < 4; ++combo) {
    const int k = combo >> 1, l = combo & 1;
    f32x4 acc[4] = {};
#pragma unroll
    for (int nt = 0; nt < 4; ++nt)
#pragma unroll
      for (int ks = 0; ks < 2; ++ks) {
        short8 af = *(const short8*)(&W4[combo][nt * 16 + l15][ks * 32 + quad * 8]);
        acc[nt] = __builtin_amdgcn_mfma_f32_16x16x32_bf16(af, bf[ks], acc[nt], 0, 0, 0);
      }
    const int wl = 2 * (wv * 16 + l15) + l;
#pragma unroll
    for (int nt = 0; nt < 4; ++nt) {
      short4v s;
#pragma unroll
      for (int r = 0; r < 4; ++r) s[r] = f2b(acc[nt][r] + BS[nt * 16 + quad * 4 + r]);
      *(short4v*)(&U[k][wl][nt * 16 + quad * 4]) = s;
    }
  }
  __syncthreads();
  short* xcat = (short*)(g_ws + OFF_XCAT);
  short* xpu = (short*)(g_ws + OFF_XPU);
  for (int rep = 0; rep < 8; ++rep) {
    int unit = rep * 256 + t;
    int k = unit >> 10, wl = (unit >> 3) & 127, cg = unit & 7;
    int h = 2 * hs + k, w = half * 128 + wl;
    *(short8*)(xcat + (((size_t)(b * 256) + h) * 256 + w) * 128 + 64 + cg * 8) =
        *(short8*)(&U[k][wl][cg * 8]);
  }
  for (int rep = 0; rep < 8; ++rep) {
    int unit = rep * 256 + t;
    int o = unit >> 5, k = (unit >> 4) & 1, wg = unit & 15;
    int h = 2 * hs + k;
    short8 v;
#pragma unroll
    for (int j = 0; j < 8; ++j) v[j] = U[k][wg * 8 + j][o];
    *(short8*)(xpu + (size_t)(b * 64 + o) * 65536 + h * 256 + half * 128 + wg * 8) = v;
  }
}

// ---------- offconv: 128->256 3x3 MFMA, row-streamed LDS double-buffer ----------
// Block = (b, h, wq): 64 px x 256 oc; wave = 64px x 64oc.
// Row buffer: 66 px x 128 ch, px-stride 130 shorts (65 words, odd -> conflict-light).
// 2 buffers = 34.3 KB -> 4 blocks/CU (16 waves/CU).
__global__ __launch_bounds__(256, 4)
void k_offconv() {
  __shared__ short R[2][66 * 130];
  const short* X = (const short*)(g_ws + OFF_XCAT);
  const __hip_bfloat16* W = (const __hip_bfloat16*)(g_ws + OFF_WO);
  const int t = threadIdx.x;
  const int wq = blockIdx.x & 3, h = (blockIdx.x >> 2) & 255, b = blockIdx.x >> 10;
  const int w0 = wq * 64;
  const int wv = t >> 6, lane = t & 63, l15 = lane & 15, quad = lane >> 4;
  const int ocbase = wv * 64;
  const size_t rowstride = 256 * 128;
  const short* xb = X + (size_t)(b * 256) * rowstride + (size_t)(w0 - 1) * 128;

  // stage row h-1 into R[0]  (1056 short8 units: px=u>>4, cg=u&15)
  {
    const int grow = h - 1;
#pragma unroll
    for (int k = 0; k < 5; ++k) {
      int u = t + k * 256;
      if (u < 1056) {
        int px = u >> 4, cg = u & 15;
        int gpx = w0 - 1 + px;
        short8 v = {};
        if ((unsigned)grow < 256u && (unsigned)gpx < 256u)
          v = *(const short8*)(xb + (size_t)grow * rowstride + px * 128 + cg * 8);
        *(short8*)(&R[0][px * 130 + cg * 8]) = v;
      }
    }
  }
  __syncthreads();

  f32x4 acc[4][4] = {};
#pragma unroll
  for (int ky = 0; ky < 3; ++ky) {
    const int cur = ky & 1;
    short8 tmp[5];
    if (ky < 2) {
      const int grow = h + ky;
      const bool rok = (unsigned)grow < 256u;
#pragma unroll
      for (int k = 0; k < 5; ++k) {
        int u = t + k * 256;
        int px = u >> 4, cg = u & 15;
        int gpx = w0 - 1 + px;
        short8 v = {};
        if (u < 1056 && rok && (unsigned)gpx < 256u)
          v = *(const short8*)(xb + (size_t)grow * rowstride + px * 128 + cg * 8);
        tmp[k] = v;
      }
    }
#pragma unroll
    for (int kx = 0; kx < 3; ++kx) {
      const int tap = ky * 3 + kx;
      const __hip_bfloat16* wtap = W + ((size_t)tap * 256 + ocbase + l15) * 128 + quad * 8;
      const short* srow = &R[cur][(l15 + kx) * 130 + quad * 8];
#pragma unroll
      for (int ics = 0; ics < 4; ++ics) {
        short8 a[4], bf[4];
#pragma unroll
        for (int ot = 0; ot < 4; ++ot)
          a[ot] = *(const short8*)(wtap + ot * 16 * 128 + ics * 32);
#pragma unroll
        for (int pt = 0; pt < 4; ++pt)
          bf[pt] = *(const short8*)(srow + pt * 16 * 130 + ics * 32);
#pragma unroll
        for (int ot = 0; ot < 4; ++ot)
#pragma unroll
          for (int pt = 0; pt < 4; ++pt)
            acc[ot][pt] = __builtin_amdgcn_mfma_f32_16x16x32_bf16(a[ot], bf[pt], acc[ot][pt], 0, 0, 0);
      }
    }
    if (ky < 2) {
#pragma unroll
      for (int k = 0; k < 5; ++k) {
        int u = t + k * 256;
        if (u < 1056) {
          int px = u >> 4, cg = u & 15;
          *(short8*)(&R[cur ^ 1][px * 130 + cg * 8]) = tmp[k];
        }
      }
    }
    __syncthreads();
  }
  __hip_bfloat16* out = (__hip_bfloat16*)(g_ws + OFF_OFF);  // NCHW (B,256,256,256)
#pragma unroll
  for (int ot = 0; ot < 4; ++ot)
#pragma unroll
    for (int pt = 0; pt < 4; ++pt)
#pragma unroll
      for (int r = 0; r < 4; ++r) {
        int oc = ocbase + ot * 16 + quad * 4 + r;
        int px = w0 + pt * 16 + l15;
        out[(((size_t)(b * 256 + oc)) * 256 + h) * 256 + px] =
            __float2bfloat16(acc[ot][pt][r]);
      }
}

// ---------- MFMA implicit-GEMM 3x3 conv (OC=64), 1024-block grid ----------
// Block = (b, h, half): 128 px x 64 oc; wave = 32 px x 64 oc (4x2 tiles).
template <int IC>
__global__ __launch_bounds__(256)
void k_convsm(size_t xoff, size_t woff, const float* __restrict__ bias, size_t ooff) {
  const __hip_bfloat16* X = (const __hip_bfloat16*)(g_ws + xoff);
  const __hip_bfloat16* W = (const __hip_bfloat16*)(g_ws + woff);
  const int t = threadIdx.x;
  const int wv = t >> 6, lane = t & 63, l15 = lane & 15, quad = lane >> 4;
  const int half = blockIdx.x & 1, h = (blockIdx.x >> 1) & 255, b = blockIdx.x >> 9;
  const int pixb = half * 128 + wv * 32;
  const int KS = IC / 32;
  f32x4 acc[4][2] = {};
  for (int tap = 0; tap < 9; ++tap) {
    const int ky = tap / 3, kx = tap - 3 * ky;
    const int row = h + ky - 1;
    const bool rowok = (unsigned)row < 256u;
    int pix[2]; bool pok[2];
#pragma unroll
    for (int pt = 0; pt < 2; ++pt) {
      pix[pt] = pixb + pt * 16 + l15 + kx - 1;
      pok[pt] = rowok && (unsigned)pix[pt] < 256u;
    }
    const __hip_bfloat16* wtap = W + ((size_t)tap * 64 + l15) * IC + quad * 8;
    const __hip_bfloat16* xrow = X + (((size_t)(b * 256) + row) * 256) * IC + quad * 8;
#pragma unroll
    for (int ics = 0; ics < KS; ++ics) {
      short8 a[4];
#pragma unroll
      for (int ot = 0; ot < 4; ++ot)
        a[ot] = *(const short8*)(wtap + ot * 16 * IC + ics * 32);
      short8 bf[2];
#pragma unroll
      for (int pt = 0; pt < 2; ++pt) {
        short8 z = {};
        bf[pt] = pok[pt] ? *(const short8*)(xrow + (size_t)pix[pt] * IC + ics * 32) : z;
      }
#pragma unroll
      for (int ot = 0; ot < 4; ++ot)
#pragma unroll
        for (int pt = 0; pt < 2; ++pt)
          acc[ot][pt] = __builtin_amdgcn_mfma_f32_16x16x32_bf16(a[ot], bf[pt], acc[ot][pt], 0, 0, 0);
    }
  }
  __hip_bfloat16* out = (__hip_bfloat16*)(g_ws + ooff);  // NHWC (B,256,256,64)
#pragma unroll
  for (int ot = 0; ot < 4; ++ot) {
    int oc0 = ot * 16 + quad * 4;
    float bv[4];
#pragma unroll
    for (int r = 0; r < 4; ++r) bv[r] = bias[oc0 + r];
#pragma unroll
    for (int pt = 0; pt < 2; ++pt) {
      int px = pixb + pt * 16 + l15;
      short4v s;
#pragma unroll
      for (int r = 0; r < 4; ++r) s[r] = f2b(acc[ot][pt][r] + bv[r]);
      *(short4v*)(out + ((((size_t)(b * 256) + h) * 256 + px) * 64 + oc0)) = s;
    }
  }
}

// ---------- deform gather: planar sources (x2 f32, XPU bf16) -> xd NHWC bf16 ----------
__global__ __launch_bounds__(256)
void k_gather(const float* __restrict__ x2) {
  __shared__ short G[256 * 130];
  const __hip_bfloat16* off = (const __hip_bfloat16*)(g_ws + OFF_OFF);
  const __hip_bfloat16* xpu = (const __hip_bfloat16*)(g_ws + OFF_XPU);
  short* xd = (short*)(g_ws + OFF_XD);
  const int t = threadIdx.x;
  const int hh = blockIdx.x & 255, b = blockIdx.x >> 8;
  const int hp = 2 * (hh & 127) + (t >> 7);
  const int w0e = 2 * (t & 127);
  const int chb = hh >> 7;
  const float fh = (float)hh, fw = (float)t;
  const __hip_bfloat16* offb = off + ((size_t)(b * 256) * 256 + hp) * 256 + w0e;
  const float* x2b = x2 + (size_t)b * 64 * 65536;
  const __hip_bfloat16* xub = xpu + (size_t)b * 64 * 65536;
  for (int c = 0; c < 128; ++c) {
    unsigned ov = *(const unsigned*)(offb + (size_t)(2 * c + chb) * 65536);
    float oy = __uint_as_float((ov & 0xffffu) << 16);
    float ox = __uint_as_float((ov >> 16) << 16);
    float cy = fminf(fmaxf(oy + fh, 0.f), 255.f);
    float cx = fminf(fmaxf(ox + fw, 0.f), 255.f);
    float y0f = floorf(cy), x0f = floorf(cx);
    int y0 = (int)y0f, x0 = (int)x0f;
    int y1 = (int)ceilf(cy), x1 = (int)ceilf(cx);
    float v00, v10, v01, v11;
    if (c < 64) {
      const float* pl = x2b + (size_t)c * 65536;
      v00 = pl[y0 * 256 + x0]; v10 = pl[y1 * 256 + x0];
      v01 = pl[y0 * 256 + x1]; v11 = pl[y1 * 256 + x1];
    } else {
      const __hip_bfloat16* pl = xub + (size_t)(c - 64) * 65536;
      v00 = b2f(pl[y0 * 256 + x0]); v10 = b2f(pl[y1 * 256 + x0]);
      v01 = b2f(pl[y0 * 256 + x1]); v11 = b2f(pl[y1 * 256 + x1]);
    }
    float wy = cy - y0f, wx = cx - x0f;
    float vt = v00 + (v10 - v00) * wy;
    float vb = v01 + (v11 - v01) * wy;
    G[t * 130 + c] = f2b(vt + (vb - vt) * wx);
  }
  __syncthreads();
  const size_t dst = (size_t)(b * 256 + hh) * 256 * 128;
  for (int it = 0; it < 16; ++it) {
    int g = it * 256 + t;
    *(short8*)(xd + dst + (size_t)g * 8) = *(short8*)(&G[(g >> 4) * 130 + (g & 15) * 8]);
  }
}

// ---------- BN stats: NHWC bf16 (64 ch), coalesced short8 reads ----------
template <int SO>
__global__ __launch_bounds__(256)
void k_stats(size_t xoff) {
  const __hip_bfloat16* x = (const __hip_bfloat16*)(g_ws + xoff);
  __shared__ float P[256][9], P2[256][9];
  const int t = threadIdx.x;
  const int c0 = (t & 7) * 8;
  const int pg = t >> 3;
  float s[8] = {}, s2[8] = {};
  const size_t base = (size_t)blockIdx.x * 512;
  for (int i = 0; i < 16; ++i) {
    size_t p = base + pg + (size_t)i * 32;
    short8 v = *(const short8*)(x + p * 64 + c0);
#pragma unroll
    for (int j = 0; j < 8; ++j) {
      float f = s2f(v[j]);
      s[j] += f; s2[j] = fmaf(f, f, s2[j]);
    }
  }
#pragma unroll
  for (int j = 0; j < 8; ++j) { P[t][j] = s[j]; P2[t][j] = s2[j]; }
  __syncthreads();
  if (t < 64) {
    int cg = t >> 3, j = t & 7;
    float a = 0.f, a2 = 0.f;
    for (int kk = 0; kk < 32; ++kk) { a += P[kk * 8 + cg][j]; a2 += P2[kk * 8 + cg][j]; }
    atomicAdd(&g_st[SO + t], a);
    atomicAdd(&g_st[SO + 64 + t], a2);
  }
}

template <int SO>
__global__ void k_finstat() {
  int c = threadIdx.x;
  if (c < 64) {
    float m = g_st[SO + c] * (1.f / 131072.f);
    float v = g_st[SO + 64 + c] * (1.f / 131072.f) - m * m;
    g_st[SO + c] = m;
    g_st[SO + 64 + c] = rsqrtf(v + 1e-5f);
  }
}

// ---------- BN apply + ReLU: c1o NHWC -> h1 NHWC bf16 ----------
__global__ __launch_bounds__(256)
void k_bnrelu1(const float* __restrict__ g, const float* __restrict__ be) {
  const __hip_bfloat16* x = (const __hip_bfloat16*)(g_ws + OFF_C1O);
  __hip_bfloat16* o = (__hip_bfloat16*)(g_ws + OFF_H1);
  size_t idx = ((size_t)blockIdx.x * 256 + threadIdx.x) * 8;
  int c0 = (int)(idx & 63);
  short8 v = *(const short8*)(x + idx);
  short8 r;
#pragma unroll
  for (int j = 0; j < 8; ++j) {
    int c = c0 + j;
    float f = (s2f(v[j]) - g_st[c]) * g_st[64 + c] * g[c] + be[c];
    r[j] = f2b(fmaxf(f, 0.f));
  }
  *(short8*)(o + idx) = r;
}

// ---------- BN apply + ReLU + NHWC->NCHW f32 to d_out ----------
__global__ __launch_bounds__(256)
void k_bnrelu2(const float* __restrict__ g, const float* __restrict__ be,
               float* __restrict__ dout) {
  __shared__ float T[64 * 257];
  const __hip_bfloat16* x = (const __hip_bfloat16*)(g_ws + OFF_C2O);
  const int t = threadIdx.x;
  const int h = blockIdx.x & 255, b = blockIdx.x >> 8;
  const __hip_bfloat16* px = x + (((size_t)(b * 256) + h) * 256 + t) * 64;
#pragma unroll
  for (int cg = 0; cg < 8; ++cg) {
    short8 v = *(const short8*)(px + cg * 8);
#pragma unroll
    for (int j = 0; j < 8; ++j) {
      int c = cg * 8 + j;
      float f = (s2f(v[j]) - g_st[128 + c]) * g_st[192 + c] * g[c] + be[c];
      T[c * 257 + t] = fmaxf(f, 0.f);
    }
  }
  __syncthreads();
  for (int rep = 0; rep < 64; ++rep) {
    int flat = rep * 256 + t, c = flat >> 8, w = flat & 255;
    dout[(((size_t)(b * 64 + c)) * 256 + h) * 256 + w] = T[c * 257 + w];
  }
}

extern "C" void kernel_launch(void* const* d_in, const int* in_sizes, int n_in,
                              void* d_out, int out_size, void* d_ws, size_t ws_size,
                              hipStream_t stream) {
  const bool ok = (n_in == 13) &&
                  in_sizes[0] == 2097152 && in_sizes[1] == 8388608 &&
                  in_sizes[2] == 16384 && in_sizes[3] == 64 &&
                  in_sizes[4] == 294912 && in_sizes[5] == 73728 &&
                  in_sizes[9] == 36864 && out_size == 8388608;
  if (!ok) { hipMemsetAsync(d_out, 0x46, (size_t)out_size * 2, stream); return; }

  const float* x1   = (const float*)d_in[0];
  const float* x2   = (const float*)d_in[1];
  const float* up_w = (const float*)d_in[2];
  const float* up_b = (const float*)d_in[3];
  const float* offw = (const float*)d_in[4];
  const float* c1w  = (const float*)d_in[5];
  const float* c1b  = (const float*)d_in[6];
  const float* g1   = (const float*)d_in[7];
  const float* b1   = (const float*)d_in[8];
  const float* c2w  = (const float*)d_in[9];
  const float* c2b  = (const float*)d_in[10];
  const float* g2   = (const float*)d_in[11];
  const float* b2   = (const float*)d_in[12];

  k_prep<<<1584, 256, 0, stream>>>(offw, c1w, c2w);
  k_xpose<<<512, 256, 0, stream>>>(x2);
  k_upmfma<<<512, 256, 0, stream>>>(x1, up_w, up_b);
  k_offconv<<<2048, 256, 0, stream>>>();
  k_gather<<<512, 256, 0, stream>>>(x2);
  k_convsm<128><<<1024, 256, 0, stream>>>(OFF_XD, OFF_W1, c1b, OFF_C1O);
  k_stats<0><<<256, 256, 0, stream>>>(OFF_C1O);
  k_finstat<0><<<1, 64, 0, stream>>>();
  k_bnrelu1<<<4096, 256, 0, stream>>>(g1, b1);
  k_convsm<64><<<1024, 256, 0, stream>>>(OFF_H1, OFF_W2, c2b, OFF_C2O);
  k_stats<128><<<256, 256, 0, stream>>>(OFF_C2O);
  k_finstat<128><<<1, 64, 0, stream>>>();
  k_bnrelu2<<<512, 256, 0, stream>>>(g2, b2, (float*)d_out);

  (void)d_ws; (void)ws_size;
}

// Round 11
// 515.035 us; speedup vs baseline: 1.2018x; 1.2018x over previous
//
#include <hip/hip_runtime.h>
#include <hip/hip_bf16.h>

// Problem: B=2, Ccat=128, OUT=64, H=W=256, f32 in/out storage, bf16-grade 2% tol.
// Pipeline:
//   prep: weights -> [tap][oc][ic] bf16; zero stats
//   xpose: x2 NCHW -> xcat NHWC lower 64ch
//   upmfma: convT2x2 (MFMA, 4 parity GEMMs) -> xcat upper 64ch + planar XPU
//   offconv (MFMA, 2-phase K-split, 28.5KB LDS, 3 blocks/CU): 128->256 -> off NCHW
//   gather: bilinear deform (planar sources) -> xd NHWC bf16
//   conv1 (MFMA) + bias -> c1o NHWC; stats; bnrelu -> h1 NHWC
//   conv2 (MFMA) + bias -> c2o NHWC; stats; bnrelu+xpose -> d_out NCHW f32
// g_ws: xcat 0..32Mi | off 32..96Mi | xd 96..128Mi | c1o 128..144Mi | h1 144..160Mi
//       c2o 160..176Mi | Wo/W1/W2 176Mi..176Mi+811008 | XPU 177..193Mi

typedef short short8 __attribute__((ext_vector_type(8)));
typedef short short4v __attribute__((ext_vector_type(4)));
typedef float f32x4 __attribute__((ext_vector_type(4)));

__device__ unsigned char g_ws[193u << 20] __attribute__((aligned(256)));
__device__ float g_st[256];

#define OFF_XCAT 0u
#define OFF_OFF  (32u << 20)
#define OFF_XD   (96u << 20)
#define OFF_C1O  (128u << 20)
#define OFF_H1   (144u << 20)
#define OFF_C2O  (160u << 20)
#define OFF_WO   (176u << 20)
#define OFF_W1   ((176u << 20) + 589824u)
#define OFF_W2   ((176u << 20) + 737280u)
#define OFF_XPU  (177u << 20)

__device__ __forceinline__ float b2f(__hip_bfloat16 v) { return __bfloat162float(v); }
__device__ __forceinline__ short f2b(float v) {
  __hip_bfloat16 h = __float2bfloat16(v); short s; __builtin_memcpy(&s, &h, 2); return s;
}
__device__ __forceinline__ float s2f(short s) {
  __hip_bfloat16 h; __builtin_memcpy(&h, &s, 2); return __bfloat162float(h);
}

// ---------- prep: weight transforms (OIHW f32 -> [tap][oc][ic] bf16) + zero stats ----------
__global__ __launch_bounds__(256)
void k_prep(const float* __restrict__ offw, const float* __restrict__ c1w,
            const float* __restrict__ c2w) {
  const int fid = blockIdx.x * 256 + threadIdx.x;
  if (blockIdx.x == 0) g_st[threadIdx.x] = 0.f;
  __hip_bfloat16* Wo = (__hip_bfloat16*)(g_ws + OFF_WO);
  __hip_bfloat16* W1 = (__hip_bfloat16*)(g_ws + OFF_W1);
  __hip_bfloat16* W2 = (__hip_bfloat16*)(g_ws + OFF_W2);
  if (fid < 294912) {            // Wo: (tap*256+oc)*128+ic
    int ic = fid & 127, rest = fid >> 7, oc = rest & 255, tap = rest >> 8;
    Wo[fid] = __float2bfloat16(offw[(oc * 128 + ic) * 9 + tap]);
  } else if (fid < 368640) {     // W1: (tap*64+oc)*128+ic
    int l = fid - 294912;
    int ic = l & 127, rest = l >> 7, oc = rest & 63, tap = rest >> 6;
    W1[l] = __float2bfloat16(c1w[(oc * 128 + ic) * 9 + tap]);
  } else {                       // W2: (tap*64+oc)*64+ic
    int l = fid - 368640;
    int ic = l & 63, rest = l >> 6, oc = rest & 63, tap = rest >> 6;
    W2[l] = __float2bfloat16(c2w[(oc * 64 + ic) * 9 + tap]);
  }
}

// ---------- xpose: x2 NCHW f32 -> xcat NHWC bf16 lower 64 channels ----------
__global__ __launch_bounds__(256)
void k_xpose(const float* __restrict__ x2) {
  __shared__ short T[256][72];
  const int t = threadIdx.x;
  const int h = blockIdx.x & 255, b = blockIdx.x >> 8;
  const float* src = x2 + (size_t)(b * 64) * 65536 + h * 256;
  for (int rep = 0; rep < 64; ++rep) {
    int flat = rep * 256 + t, c = flat >> 8, w = flat & 255;
    T[w][c] = f2b(src[(size_t)c * 65536 + w]);
  }
  __syncthreads();
  short* xcat = (short*)(g_ws + OFF_XCAT) + ((size_t)(b * 256 + h) * 256) * 128;
  for (int rep = 0; rep < 8; ++rep) {
    int unit = rep * 256 + t;  // w*8+cg
    int w = unit >> 3, cg = unit & 7;
    *(short8*)(xcat + (size_t)w * 128 + cg * 8) = *(short8*)(&T[w][cg * 8]);
  }
}

// ---------- upmfma: convT(2x2,s2) via 4 parity GEMMs -> xcat upper + XPU planar ----------
__global__ __launch_bounds__(256)
void k_upmfma(const float* __restrict__ x1, const float* __restrict__ up_w,
              const float* __restrict__ up_b) {
  __shared__ short W4[4][64][66];   // [k*2+l][o][i]
  __shared__ short X[64][68];       // [ws][i]
  __shared__ short U[2][128][66];   // [k][wl][o]
  __shared__ float BS[64];
  const int t = threadIdx.x;
  const int half = blockIdx.x & 1, hs = (blockIdx.x >> 1) & 127, b = blockIdx.x >> 8;
  for (int rep = 0; rep < 64; ++rep) {
    int flat = rep * 256 + t;
    int i = flat >> 8, rest = flat & 255, o = rest >> 2, kl = rest & 3;
    W4[kl][o][i] = f2b(up_w[flat]);
  }
  if (t < 64) BS[t] = up_b[t];
  const float* x1b = x1 + (size_t)(b * 64) * 16384 + hs * 128 + half * 64;
  for (int rep = 0; rep < 16; ++rep) {
    int flat = rep * 256 + t;
    int i = flat >> 6, ws = flat & 63;
    X[ws][i] = f2b(x1b[(size_t)i * 16384 + ws]);
  }
  __syncthreads();
  const int wv = t >> 6, lane = t & 63, l15 = lane & 15, quad = lane >> 4;
  short8 bf[2];
#pragma unroll
  for (int ks = 0; ks < 2; ++ks)
    bf[ks] = *(const short8*)(&X[wv * 16 + l15][ks * 32 + quad * 8]);
#pragma unroll
  for (int combo = 0; combo < 4; ++combo) {
    const int k = combo >> 1, l = combo & 1;
    f32x4 acc[4] = {};
#pragma unroll
    for (int nt = 0; nt < 4; ++nt)
#pragma unroll
      for (int ks = 0; ks < 2; ++ks) {
        short8 af = *(const short8*)(&W4[combo][nt * 16 + l15][ks * 32 + quad * 8]);
        acc[nt] = __builtin_amdgcn_mfma_f32_16x16x32_bf16(af, bf[ks], acc[nt], 0, 0, 0);
      }
    const int wl = 2 * (wv * 16 + l15) + l;
#pragma unroll
    for (int nt = 0; nt < 4; ++nt) {
      short4v s;
#pragma unroll
      for (int r = 0; r < 4; ++r) s[r] = f2b(acc[nt][r] + BS[nt * 16 + quad * 4 + r]);
      *(short4v*)(&U[k][wl][nt * 16 + quad * 4]) = s;
    }
  }
  __syncthreads();
  short* xcat = (short*)(g_ws + OFF_XCAT);
  short* xpu = (short*)(g_ws + OFF_XPU);
  for (int rep = 0; rep < 8; ++rep) {
    int unit = rep * 256 + t;
    int k = unit >> 10, wl = (unit >> 3) & 127, cg = unit & 7;
    int h = 2 * hs + k, w = half * 128 + wl;
    *(short8*)(xcat + (((size_t)(b * 256) + h) * 256 + w) * 128 + 64 + cg * 8) =
        *(short8*)(&U[k][wl][cg * 8]);
  }
  for (int rep = 0; rep < 8; ++rep) {
    int unit = rep * 256 + t;
    int o = unit >> 5, k = (unit >> 4) & 1, wg = unit & 15;
    int h = 2 * hs + k;
    short8 v;
#pragma unroll
    for (int j = 0; j < 8; ++j) v[j] = U[k][wg * 8 + j][o];
    *(short8*)(xpu + (size_t)(b * 64 + o) * 65536 + h * 256 + half * 128 + wg * 8) = v;
  }
}

// ---------- offconv: 128->256 3x3 MFMA, 2-phase K-split LDS strip ----------
// Block = (b, h, wq): 64 px x 256 oc; wave = 64px x 64oc (4x4 tiles).
// Phase p stages ch[64p,64p+64) of the 3x66 strip into one 28.5 KB buffer
// (px stride 72 shorts), computes 9 taps x 2 ics; acc persists across phases.
// LDS 28.5 KB + launch_bounds(256,3) -> 3 blocks/CU, VGPR cap ~170 (no spill).
__global__ __launch_bounds__(256, 3)
void k_offconv() {
  __shared__ short R[3 * 66 * 72];   // 28512 B
  const short* X = (const short*)(g_ws + OFF_XCAT);
  const __hip_bfloat16* W = (const __hip_bfloat16*)(g_ws + OFF_WO);
  const int t = threadIdx.x;
  const int wq = blockIdx.x & 3, h = (blockIdx.x >> 2) & 255, b = blockIdx.x >> 10;
  const int w0 = wq * 64;
  const int wv = t >> 6, lane = t & 63, l15 = lane & 15, quad = lane >> 4;
  const int ocbase = wv * 64;
  const short* xb = X + (size_t)(b * 256) * 256 * 128;
  f32x4 acc[4][4] = {};
#pragma unroll
  for (int p = 0; p < 2; ++p) {
    if (p) __syncthreads();   // all waves done reading phase 0
    // stage: 3 rows x 66 px x 8 ch-octets (1584 units, cg fastest -> 128B/8 lanes)
    for (int u = t; u < 1584; u += 256) {
      int cg = u & 7, pr = u >> 3;
      int px = pr % 66, r = pr / 66;
      int grow = h + r - 1, gpx = w0 - 1 + px;
      short8 v = {};
      if ((unsigned)grow < 256u && (unsigned)gpx < 256u)
        v = *(const short8*)(xb + ((size_t)grow * 256 + gpx) * 128 + p * 64 + cg * 8);
      *(short8*)(&R[(r * 66 + px) * 72 + cg * 8]) = v;
    }
    __syncthreads();
#pragma unroll
    for (int tap = 0; tap < 9; ++tap) {
      const int ky = tap / 3, kx = tap - 3 * ky;
      const __hip_bfloat16* wtap =
          W + ((size_t)tap * 256 + ocbase + l15) * 128 + p * 64 + quad * 8;
      const short* srow = &R[(ky * 66 + l15 + kx) * 72 + quad * 8];
#pragma unroll
      for (int ics = 0; ics < 2; ++ics) {
        short8 a[4], bf[4];
#pragma unroll
        for (int ot = 0; ot < 4; ++ot)
          a[ot] = *(const short8*)(wtap + ot * 16 * 128 + ics * 32);
#pragma unroll
        for (int pt = 0; pt < 4; ++pt)
          bf[pt] = *(const short8*)(srow + pt * 16 * 72 + ics * 32);
#pragma unroll
        for (int ot = 0; ot < 4; ++ot)
#pragma unroll
          for (int pt = 0; pt < 4; ++pt)
            acc[ot][pt] = __builtin_amdgcn_mfma_f32_16x16x32_bf16(a[ot], bf[pt], acc[ot][pt], 0, 0, 0);
      }
    }
  }
  __hip_bfloat16* out = (__hip_bfloat16*)(g_ws + OFF_OFF);  // NCHW (B,256,256,256)
#pragma unroll
  for (int ot = 0; ot < 4; ++ot)
#pragma unroll
    for (int pt = 0; pt < 4; ++pt)
#pragma unroll
      for (int r = 0; r < 4; ++r) {
        int oc = ocbase + ot * 16 + quad * 4 + r;
        int px = w0 + pt * 16 + l15;
        out[(((size_t)(b * 256 + oc)) * 256 + h) * 256 + px] =
            __float2bfloat16(acc[ot][pt][r]);
      }
}

// ---------- MFMA implicit-GEMM 3x3 conv (OC=64), 512-block grid (reverted) ----------
template <int IC>
__global__ __launch_bounds__(256, 2)
void k_convmfma(size_t xoff, size_t woff, const float* __restrict__ bias, size_t ooff) {
  const __hip_bfloat16* X = (const __hip_bfloat16*)(g_ws + xoff);
  const __hip_bfloat16* W = (const __hip_bfloat16*)(g_ws + woff);
  const int t = threadIdx.x;
  const int wv = t >> 6, lane = t & 63, l15 = lane & 15, quad = lane >> 4;
  const int h = blockIdx.x & 255, b = blockIdx.x >> 8;
  const int pixw = wv * 64;
  const int KS = IC / 32;
  f32x4 acc[4][4] = {};
  for (int tap = 0; tap < 9; ++tap) {
    const int ky = tap / 3, kx = tap - 3 * ky;
    const int row = h + ky - 1;
    const bool rowok = (unsigned)row < 256u;
    int pix[4]; bool pok[4];
#pragma unroll
    for (int pt = 0; pt < 4; ++pt) {
      pix[pt] = pixw + pt * 16 + l15 + kx - 1;
      pok[pt] = rowok && (unsigned)pix[pt] < 256u;
    }
    const __hip_bfloat16* wtap = W + ((size_t)tap * 64 + l15) * IC + quad * 8;
    const __hip_bfloat16* xrow = X + (((size_t)(b * 256) + row) * 256) * IC + quad * 8;
#pragma unroll
    for (int ics = 0; ics < KS; ++ics) {
      short8 a[4];
#pragma unroll
      for (int ot = 0; ot < 4; ++ot)
        a[ot] = *(const short8*)(wtap + ot * 16 * IC + ics * 32);
      short8 bf[4];
#pragma unroll
      for (int pt = 0; pt < 4; ++pt) {
        short8 z = {};
        bf[pt] = pok[pt] ? *(const short8*)(xrow + (size_t)pix[pt] * IC + ics * 32) : z;
      }
#pragma unroll
      for (int ot = 0; ot < 4; ++ot)
#pragma unroll
        for (int pt = 0; pt < 4; ++pt)
          acc[ot][pt] = __builtin_amdgcn_mfma_f32_16x16x32_bf16(a[ot], bf[pt], acc[ot][pt], 0, 0, 0);
    }
  }
  __hip_bfloat16* out = (__hip_bfloat16*)(g_ws + ooff);  // NHWC (B,256,256,64)
#pragma unroll
  for (int ot = 0; ot < 4; ++ot) {
    int oc0 = ot * 16 + quad * 4;
    float bv[4];
#pragma unroll
    for (int r = 0; r < 4; ++r) bv[r] = bias[oc0 + r];
#pragma unroll
    for (int pt = 0; pt < 4; ++pt) {
      int px = pixw + pt * 16 + l15;
      short4v s;
#pragma unroll
      for (int r = 0; r < 4; ++r) s[r] = f2b(acc[ot][pt][r] + bv[r]);
      *(short4v*)(out + ((((size_t)(b * 256) + h) * 256 + px) * 64 + oc0)) = s;
    }
  }
}

// ---------- deform gather: planar sources (x2 f32, XPU bf16) -> xd NHWC bf16 ----------
__global__ __launch_bounds__(256)
void k_gather(const float* __restrict__ x2) {
  __shared__ short G[256 * 130];
  const __hip_bfloat16* off = (const __hip_bfloat16*)(g_ws + OFF_OFF);
  const __hip_bfloat16* xpu = (const __hip_bfloat16*)(g_ws + OFF_XPU);
  short* xd = (short*)(g_ws + OFF_XD);
  const int t = threadIdx.x;
  const int hh = blockIdx.x & 255, b = blockIdx.x >> 8;
  const int hp = 2 * (hh & 127) + (t >> 7);
  const int w0e = 2 * (t & 127);
  const int chb = hh >> 7;
  const float fh = (float)hh, fw = (float)t;
  const __hip_bfloat16* offb = off + ((size_t)(b * 256) * 256 + hp) * 256 + w0e;
  const float* x2b = x2 + (size_t)b * 64 * 65536;
  const __hip_bfloat16* xub = xpu + (size_t)b * 64 * 65536;
  for (int c = 0; c < 128; ++c) {
    unsigned ov = *(const unsigned*)(offb + (size_t)(2 * c + chb) * 65536);
    float oy = __uint_as_float((ov & 0xffffu) << 16);
    float ox = __uint_as_float((ov >> 16) << 16);
    float cy = fminf(fmaxf(oy + fh, 0.f), 255.f);
    float cx = fminf(fmaxf(ox + fw, 0.f), 255.f);
    float y0f = floorf(cy), x0f = floorf(cx);
    int y0 = (int)y0f, x0 = (int)x0f;
    int y1 = (int)ceilf(cy), x1 = (int)ceilf(cx);
    float v00, v10, v01, v11;
    if (c < 64) {
      const float* pl = x2b + (size_t)c * 65536;
      v00 = pl[y0 * 256 + x0]; v10 = pl[y1 * 256 + x0];
      v01 = pl[y0 * 256 + x1]; v11 = pl[y1 * 256 + x1];
    } else {
      const __hip_bfloat16* pl = xub + (size_t)(c - 64) * 65536;
      v00 = b2f(pl[y0 * 256 + x0]); v10 = b2f(pl[y1 * 256 + x0]);
      v01 = b2f(pl[y0 * 256 + x1]); v11 = b2f(pl[y1 * 256 + x1]);
    }
    float wy = cy - y0f, wx = cx - x0f;
    float vt = v00 + (v10 - v00) * wy;
    float vb = v01 + (v11 - v01) * wy;
    G[t * 130 + c] = f2b(vt + (vb - vt) * wx);
  }
  __syncthreads();
  const size_t dst = (size_t)(b * 256 + hh) * 256 * 128;
  for (int it = 0; it < 16; ++it) {
    int g = it * 256 + t;
    *(short8*)(xd + dst + (size_t)g * 8) = *(short8*)(&G[(g >> 4) * 130 + (g & 15) * 8]);
  }
}

// ---------- BN stats: NHWC bf16 (64 ch), coalesced short8 reads ----------
template <int SO>
__global__ __launch_bounds__(256)
void k_stats(size_t xoff) {
  const __hip_bfloat16* x = (const __hip_bfloat16*)(g_ws + xoff);
  __shared__ float P[256][9], P2[256][9];
  const int t = threadIdx.x;
  const int c0 = (t & 7) * 8;
  const int pg = t >> 3;
  float s[8] = {}, s2[8] = {};
  const size_t base = (size_t)blockIdx.x * 512;
  for (int i = 0; i < 16; ++i) {
    size_t p = base + pg + (size_t)i * 32;
    short8 v = *(const short8*)(x + p * 64 + c0);
#pragma unroll
    for (int j = 0; j < 8; ++j) {
      float f = s2f(v[j]);
      s[j] += f; s2[j] = fmaf(f, f, s2[j]);
    }
  }
#pragma unroll
  for (int j = 0; j < 8; ++j) { P[t][j] = s[j]; P2[t][j] = s2[j]; }
  __syncthreads();
  if (t < 64) {
    int cg = t >> 3, j = t & 7;
    float a = 0.f, a2 = 0.f;
    for (int kk = 0; kk < 32; ++kk) { a += P[kk * 8 + cg][j]; a2 += P2[kk * 8 + cg][j]; }
    atomicAdd(&g_st[SO + t], a);
    atomicAdd(&g_st[SO + 64 + t], a2);
  }
}

template <int SO>
__global__ void k_finstat() {
  int c = threadIdx.x;
  if (c < 64) {
    float m = g_st[SO + c] * (1.f / 131072.f);
    float v = g_st[SO + 64 + c] * (1.f / 131072.f) - m * m;
    g_st[SO + c] = m;
    g_st[SO + 64 + c] = rsqrtf(v + 1e-5f);
  }
}

// ---------- BN apply + ReLU: c1o NHWC -> h1 NHWC bf16 ----------
__global__ __launch_bounds__(256)
void k_bnrelu1(const float* __restrict__ g, const float* __restrict__ be) {
  const __hip_bfloat16* x = (const __hip_bfloat16*)(g_ws + OFF_C1O);
  __hip_bfloat16* o = (__hip_bfloat16*)(g_ws + OFF_H1);
  size_t idx = ((size_t)blockIdx.x * 256 + threadIdx.x) * 8;
  int c0 = (int)(idx & 63);
  short8 v = *(const short8*)(x + idx);
  short8 r;
#pragma unroll
  for (int j = 0; j < 8; ++j) {
    int c = c0 + j;
    float f = (s2f(v[j]) - g_st[c]) * g_st[64 + c] * g[c] + be[c];
    r[j] = f2b(fmaxf(f, 0.f));
  }
  *(short8*)(o + idx) = r;
}

// ---------- BN apply + ReLU + NHWC->NCHW f32 to d_out ----------
__global__ __launch_bounds__(256)
void k_bnrelu2(const float* __restrict__ g, const float* __restrict__ be,
               float* __restrict__ dout) {
  __shared__ float T[64 * 257];
  const __hip_bfloat16* x = (const __hip_bfloat16*)(g_ws + OFF_C2O);
  const int t = threadIdx.x;
  const int h = blockIdx.x & 255, b = blockIdx.x >> 8;
  const __hip_bfloat16* px = x + (((size_t)(b * 256) + h) * 256 + t) * 64;
#pragma unroll
  for (int cg = 0; cg < 8; ++cg) {
    short8 v = *(const short8*)(px + cg * 8);
#pragma unroll
    for (int j = 0; j < 8; ++j) {
      int c = cg * 8 + j;
      float f = (s2f(v[j]) - g_st[128 + c]) * g_st[192 + c] * g[c] + be[c];
      T[c * 257 + t] = fmaxf(f, 0.f);
    }
  }
  __syncthreads();
  for (int rep = 0; rep < 64; ++rep) {
    int flat = rep * 256 + t, c = flat >> 8, w = flat & 255;
    dout[(((size_t)(b * 64 + c)) * 256 + h) * 256 + w] = T[c * 257 + w];
  }
}

extern "C" void kernel_launch(void* const* d_in, const int* in_sizes, int n_in,
                              void* d_out, int out_size, void* d_ws, size_t ws_size,
                              hipStream_t stream) {
  const bool ok = (n_in == 13) &&
                  in_sizes[0] == 2097152 && in_sizes[1] == 8388608 &&
                  in_sizes[2] == 16384 && in_sizes[3] == 64 &&
                  in_sizes[4] == 294912 && in_sizes[5] == 73728 &&
                  in_sizes[9] == 36864 && out_size == 8388608;
  if (!ok) { hipMemsetAsync(d_out, 0x46, (size_t)out_size * 2, stream); return; }

  const float* x1   = (const float*)d_in[0];
  const float* x2   = (const float*)d_in[1];
  const float* up_w = (const float*)d_in[2];
  const float* up_b = (const float*)d_in[3];
  const float* offw = (const float*)d_in[4];
  const float* c1w  = (const float*)d_in[5];
  const float* c1b  = (const float*)d_in[6];
  const float* g1   = (const float*)d_in[7];
  const float* b1   = (const float*)d_in[8];
  const float* c2w  = (const float*)d_in[9];
  const float* c2b  = (const float*)d_in[10];
  const float* g2   = (const float*)d_in[11];
  const float* b2   = (const float*)d_in[12];

  k_prep<<<1584, 256, 0, stream>>>(offw, c1w, c2w);
  k_xpose<<<512, 256, 0, stream>>>(x2);
  k_upmfma<<<512, 256, 0, stream>>>(x1, up_w, up_b);
  k_offconv<<<2048, 256, 0, stream>>>();
  k_gather<<<512, 256, 0, stream>>>(x2);
  k_convmfma<128><<<512, 256, 0, stream>>>(OFF_XD, OFF_W1, c1b, OFF_C1O);
  k_stats<0><<<256, 256, 0, stream>>>(OFF_C1O);
  k_finstat<0><<<1, 64, 0, stream>>>();
  k_bnrelu1<<<4096, 256, 0, stream>>>(g1, b1);
  k_convmfma<64><<<512, 256, 0, stream>>>(OFF_H1, OFF_W2, c2b, OFF_C2O);
  k_stats<128><<<256, 256, 0, stream>>>(OFF_C2O);
  k_finstat<128><<<1, 64, 0, stream>>>();
  k_bnrelu2<<<512, 256, 0, stream>>>(g2, b2, (float*)d_out);

  (void)d_ws; (void)ws_size;
}